// Round 7
// baseline (363.030 us; speedup 1.0000x reference)
//
#include <hip/hip_runtime.h>

typedef unsigned short u16;
typedef __attribute__((ext_vector_type(8))) short short8;
typedef __attribute__((ext_vector_type(8))) unsigned short ushort8v;
typedef __attribute__((ext_vector_type(4))) float f32x4;

#define B_ 8
#define T_ 256
#define U_ 64
#define E_ 512
#define J_ 640
#define V_ 1024

__device__ __forceinline__ u16 f2bf(float f) {
  unsigned int u = __float_as_uint(f);
  u += 0x7fffu + ((u >> 16) & 1u);   // round-to-nearest-even
  return (u16)(u >> 16);
}

__device__ __forceinline__ void gload16(const void* g, void* l) {
  __builtin_amdgcn_global_load_lds((const __attribute__((address_space(1))) void*)g,
                                   (__attribute__((address_space(3))) void*)l,
                                   16, 0, 0);
}

// ---------------- fused cast fp32 -> bf16 for all 5 inputs (dsts contiguous in ws) --------
__global__ __launch_bounds__(256) void cast5_k(const float4* __restrict__ s0,
                                               const float4* __restrict__ s1,
                                               const float4* __restrict__ s2,
                                               const float4* __restrict__ s3,
                                               const float4* __restrict__ s4,
                                               ushort4* __restrict__ dst) {
  int i = blockIdx.x * 256 + threadIdx.x;
  const int st = gridDim.x * 256;
  for (; i < 655360; i += st) {
    const float4* s; int off;
    if (i < 262144)      { s = s0; off = 0; }
    else if (i < 327680) { s = s1; off = 262144; }
    else if (i < 409600) { s = s2; off = 327680; }
    else if (i < 491520) { s = s3; off = 409600; }
    else                 { s = s4; off = 491520; }
    float4 v = s[i - off];
    ushort4 o;
    o.x = f2bf(v.x); o.y = f2bf(v.y); o.z = f2bf(v.z); o.w = f2bf(v.w);
    dst[i] = o;
  }
}

// ---------------- projection GEMM (small, latency-tolerant) ----------------
__global__ __launch_bounds__(256) void proj_k(const u16* __restrict__ X,
                                              const u16* __restrict__ W,
                                              float* __restrict__ C) {
  __shared__ __align__(16) u16 As[128 * 32];
  __shared__ __align__(16) u16 Bs[128 * 32];
  const int tid = threadIdx.x;
  const int w = tid >> 6, lane = tid & 63;
  const int wr = w >> 1, wc = w & 1;
  const int m0 = blockIdx.x * 128, n0 = blockIdx.y * 128;
  const int lr = lane & 15, lk = lane >> 4;
  const int r4 = tid >> 2, kq = tid & 3;

  f32x4 acc[4][4] = {};

  for (int ks = 0; ks < E_ / 32; ++ks) {
    const int k0 = ks * 32;
    gload16(X + (size_t)(m0 + r4) * E_ + k0 + kq * 8, (char*)As + w * 1024);
    gload16(X + (size_t)(m0 + 64 + r4) * E_ + k0 + kq * 8, (char*)As + 4096 + w * 1024);
    gload16(W + (size_t)(n0 + r4) * E_ + k0 + kq * 8, (char*)Bs + w * 1024);
    gload16(W + (size_t)(n0 + 64 + r4) * E_ + k0 + kq * 8, (char*)Bs + 4096 + w * 1024);
    __syncthreads();
    short8 a[4], bb[4];
#pragma unroll
    for (int m = 0; m < 4; ++m)
      a[m] = *(const short8*)&As[(wr * 64 + m * 16 + lr) * 32 + lk * 8];
#pragma unroll
    for (int n = 0; n < 4; ++n)
      bb[n] = *(const short8*)&Bs[(wc * 64 + n * 16 + lr) * 32 + lk * 8];
#pragma unroll
    for (int m = 0; m < 4; ++m)
#pragma unroll
      for (int n = 0; n < 4; ++n)
        acc[m][n] = __builtin_amdgcn_mfma_f32_16x16x32_bf16(a[m], bb[n], acc[m][n], 0, 0, 0);
    __syncthreads();
  }

#pragma unroll
  for (int m = 0; m < 4; ++m) {
    const int row = m0 + wr * 64 + m * 16 + lk * 4;
#pragma unroll
    for (int n = 0; n < 4; ++n) {
      const int col = n0 + wc * 64 + n * 16 + lr;
#pragma unroll
      for (int i = 0; i < 4; ++i)
        C[(size_t)(row + i) * J_ + col] = acc[m][n][i];
    }
  }
}

// ---------------- A materializer: A[m][k] = bf16(silu(ep + pp)) ----------------
__global__ __launch_bounds__(256) void silu_k(const float* __restrict__ ep,
                                              const float* __restrict__ pp,
                                              u16* __restrict__ A, int nUnits) {
  int i = blockIdx.x * 256 + threadIdx.x;
  const int st = gridDim.x * 256;
  for (; i < nUnits; i += st) {
    const int m = i / 80;
    const int k0 = (i - m * 80) * 8;
    const int b = m >> 14;
    const int t = (m >> 6) & 255;
    const int uu = m & 63;
    const float* e = ep + (size_t)(b * T_ + t) * J_ + k0;
    const float* p = pp + (size_t)(b * U_ + uu) * J_ + k0;
    union { float4 v[2]; float f[8]; } Ee, Pp;
    Ee.v[0] = *(const float4*)e;      Ee.v[1] = *(const float4*)(e + 4);
    Pp.v[0] = *(const float4*)p;      Pp.v[1] = *(const float4*)(p + 4);
    union { ushort8v v; u16 s[8]; } R;
#pragma unroll
    for (int j = 0; j < 8; ++j) {
      float x = Ee.f[j] + Pp.f[j];
      float s = x * __builtin_amdgcn_rcpf(1.0f + __expf(-x));
      R.s[j] = f2bf(s);
    }
    *(ushort8v*)(A + (size_t)m * J_ + k0) = R.v;
  }
}

// ---------------- main GEMM: 256x256 tile, BK=64, 8 waves ----------------
// Ring-buffer schedule: 4 half-tile slots per operand (2 K-tiles), 1 barrier +
// 1 vmcnt(0) per K-tile; tile t+1's 8 stage loads issued right after tile t's
// barrier (full-tile latency cover; they overwrite tile t-1's slots, whose
// reads completed before the barrier). 4 quadrant phases interleave ds_read
// with MFMA. Chunk-XOR swizzle: LDS[row][c^(row&7)], pre-swizzled source.
#define NT2 10   // 640/64 K-tiles
__global__ __launch_bounds__(512, 2) void gemm256_k(const u16* __restrict__ A,
                                                    const u16* __restrict__ Bw,
                                                    float* __restrict__ out) {
  __shared__ __align__(16) u16 As[4][128][64];   // 64 KiB ring (A half-tiles)
  __shared__ __align__(16) u16 Bs[4][128][64];   // 64 KiB ring (B half-tiles)
  const int tid = threadIdx.x;
  const int w = tid >> 6, lane = tid & 63;
  const int wr = w >> 2, wc = w & 3;            // 2M x 4N waves, wave tile 128x64
  const int lr = lane & 15, lk = lane >> 4;
  const int rx = lane & 7;                      // read-side swizzle term (= row&7)

  // XCD-bijective swizzle: nwg=2048 = 8 XCDs x 256-chunk; nb inner for A-reuse
  const int bid = blockIdx.x;
  const int wid = (bid & 7) * 256 + (bid >> 3);
  const int mbb = wid >> 2, nbb = wid & 3;
  const size_t m0 = (size_t)mbb * 256;
  const int n0 = nbb * 256;

  // staging: thread covers row rw (and rw+64) of each half-tile, source chunk
  // pre-swizzled so linear LDS dest holds LDS[row][c ^ (row&7)]
  const int rw = tid >> 3;
  const int csrc = (tid & 7) ^ (rw & 7);
  const u16* aBase = A + (m0 + rw) * J_ + csrc * 8;
  const u16* bBase = Bw + (size_t)(n0 + rw) * J_ + csrc * 8;

  f32x4 acc[8][4] = {};

#define STAGE_T(t1)                                                            \
  do {                                                                         \
    const int s0_ = (2 * (t1)) & 3, s1_ = (2 * (t1) + 1) & 3;                  \
    const int k0_ = (t1) * 64;                                                 \
    gload16(aBase + k0_,            (char*)&As[s0_][0][0] + tid * 16);         \
    gload16(aBase + 64 * J_ + k0_,  (char*)&As[s0_][0][0] + 8192 + tid * 16);  \
    gload16(aBase + 128 * J_ + k0_, (char*)&As[s1_][0][0] + tid * 16);         \
    gload16(aBase + 192 * J_ + k0_, (char*)&As[s1_][0][0] + 8192 + tid * 16);  \
    gload16(bBase + k0_,            (char*)&Bs[s0_][0][0] + tid * 16);         \
    gload16(bBase + 64 * J_ + k0_,  (char*)&Bs[s0_][0][0] + 8192 + tid * 16);  \
    gload16(bBase + 128 * J_ + k0_, (char*)&Bs[s1_][0][0] + tid * 16);         \
    gload16(bBase + 192 * J_ + k0_, (char*)&Bs[s1_][0][0] + 8192 + tid * 16);  \
  } while (0)

  STAGE_T(0);   // prologue: tile 0 in flight

#pragma unroll 1
  for (int t = 0; t < NT2; ++t) {
    asm volatile("s_waitcnt vmcnt(0)" ::: "memory");   // tile t landed
    __builtin_amdgcn_s_barrier();                      // t-1 reads done everywhere
    __builtin_amdgcn_sched_barrier(0);
    if (t + 1 < NT2) STAGE_T(t + 1);                   // overwrite t-1 slots; full-tile cover
    __builtin_amdgcn_sched_barrier(0);

    const int sa = (2 * t + wr) & 3;                   // this wave's A half-tile slot
    const int sb = (2 * t + (wc >> 1)) & 3;            // this wave's B half-tile slot
    const int brow = (wc & 1) * 64;

    short8 bf[4][2];
#pragma unroll
    for (int nq = 0; nq < 4; ++nq)
#pragma unroll
      for (int kk = 0; kk < 2; ++kk)
        bf[nq][kk] = *(const short8*)&Bs[sb][brow + nq * 16 + lr][((kk * 4 + lk) ^ rx) * 8];

#pragma unroll
    for (int ph = 0; ph < 4; ++ph) {
      const int r0 = (ph * 2) * 16 + lr;
      const int r1 = (ph * 2 + 1) * 16 + lr;
      short8 a00 = *(const short8*)&As[sa][r0][((0 + lk) ^ rx) * 8];
      short8 a01 = *(const short8*)&As[sa][r0][((4 + lk) ^ rx) * 8];
      short8 a10 = *(const short8*)&As[sa][r1][((0 + lk) ^ rx) * 8];
      short8 a11 = *(const short8*)&As[sa][r1][((4 + lk) ^ rx) * 8];
      __builtin_amdgcn_s_setprio(1);
#pragma unroll
      for (int nq = 0; nq < 4; ++nq) {
        acc[ph * 2][nq]     = __builtin_amdgcn_mfma_f32_16x16x32_bf16(a00, bf[nq][0], acc[ph * 2][nq], 0, 0, 0);
        acc[ph * 2][nq]     = __builtin_amdgcn_mfma_f32_16x16x32_bf16(a01, bf[nq][1], acc[ph * 2][nq], 0, 0, 0);
        acc[ph * 2 + 1][nq] = __builtin_amdgcn_mfma_f32_16x16x32_bf16(a10, bf[nq][0], acc[ph * 2 + 1][nq], 0, 0, 0);
        acc[ph * 2 + 1][nq] = __builtin_amdgcn_mfma_f32_16x16x32_bf16(a11, bf[nq][1], acc[ph * 2 + 1][nq], 0, 0, 0);
      }
      __builtin_amdgcn_s_setprio(0);
      __builtin_amdgcn_sched_barrier(0);
    }
  }
#undef STAGE_T

#pragma unroll
  for (int m = 0; m < 8; ++m) {
    const size_t row = m0 + wr * 128 + m * 16 + lk * 4;
#pragma unroll
    for (int n = 0; n < 4; ++n) {
      const int col = n0 + wc * 64 + n * 16 + lr;
#pragma unroll
      for (int i = 0; i < 4; ++i)
        out[(row + i) * V_ + col] = acc[m][n][i];
    }
  }
}

// ---------------- fallback fused kernel (round-1) if ws too small ----------------
__global__ __launch_bounds__(256) void joint_k(const float* __restrict__ ep,
                                               const float* __restrict__ pp,
                                               const u16* __restrict__ Wo,
                                               float* __restrict__ out) {
  __shared__ __align__(16) u16 As[128 * 40];
  __shared__ __align__(16) u16 Bs[128 * 32];
  const int tid = threadIdx.x;
  const int w = tid >> 6, lane = tid & 63;
  const int wr = w >> 1, wc = w & 1;
  const int bid = blockIdx.x;
  const int nb = bid & 7;
  const int mb = bid >> 3;
  const int b = mb >> 7;
  const int t0 = (mb & 127) * 2;
  const int n0 = nb * 128;
  const int lr = lane & 15, lk = lane >> 4;
  const int r = tid >> 1, h = tid & 1;
  const float* eprow = ep + (size_t)((b * T_ + t0 + (r >> 6)) * J_ + h * 16);
  const float* pprow = pp + (size_t)((b * U_ + (r & 63)) * J_ + h * 16);
  u16* awp = &As[r * 40 + h * 16];
  const int r4 = tid >> 2, kq = tid & 3;

  f32x4 acc[4][4] = {};

  for (int ks = 0; ks < J_ / 32; ++ks) {
    const int k0 = ks * 32;
    gload16(Wo + (size_t)(n0 + r4) * J_ + k0 + kq * 8, (char*)Bs + w * 1024);
    gload16(Wo + (size_t)(n0 + 64 + r4) * J_ + k0 + kq * 8, (char*)Bs + 4096 + w * 1024);
    union { float4 v[4]; float f[16]; } Ee, Pp;
#pragma unroll
    for (int j = 0; j < 4; ++j) {
      Ee.v[j] = *(const float4*)(eprow + k0 + j * 4);
      Pp.v[j] = *(const float4*)(pprow + k0 + j * 4);
    }
    union { ushort8v v[2]; u16 s[16]; } R;
#pragma unroll
    for (int j = 0; j < 16; ++j) {
      float x = Ee.f[j] + Pp.f[j];
      float s = x * __builtin_amdgcn_rcpf(1.0f + __expf(-x));
      R.s[j] = f2bf(s);
    }
    *(ushort8v*)awp = R.v[0];
    *(ushort8v*)(awp + 8) = R.v[1];
    __syncthreads();

    short8 a[4], bb[4];
#pragma unroll
    for (int m = 0; m < 4; ++m)
      a[m] = *(const short8*)&As[(wr * 64 + m * 16 + lr) * 40 + lk * 8];
#pragma unroll
    for (int n = 0; n < 4; ++n)
      bb[n] = *(const short8*)&Bs[(wc * 64 + n * 16 + lr) * 32 + lk * 8];
#pragma unroll
    for (int m = 0; m < 4; ++m)
#pragma unroll
      for (int n = 0; n < 4; ++n)
        acc[m][n] = __builtin_amdgcn_mfma_f32_16x16x32_bf16(a[m], bb[n], acc[m][n], 0, 0, 0);
    __syncthreads();
  }

  const size_t mbase = (size_t)mb * 128;
#pragma unroll
  for (int m = 0; m < 4; ++m) {
    const size_t row = mbase + wr * 64 + m * 16 + lk * 4;
#pragma unroll
    for (int n = 0; n < 4; ++n) {
      const int col = n0 + wc * 64 + n * 16 + lr;
#pragma unroll
      for (int i = 0; i < 4; ++i)
        out[(row + i) * V_ + col] = acc[m][n][i];
    }
  }
}

extern "C" void kernel_launch(void* const* d_in, const int* in_sizes, int n_in,
                              void* d_out, int out_size, void* d_ws, size_t ws_size,
                              hipStream_t stream) {
  const float* enc = (const float*)d_in[0];   // [8,256,512]
  const float* pred = (const float*)d_in[1];  // [8,64,512]
  const float* We = (const float*)d_in[2];    // [640,512]
  const float* Wp = (const float*)d_in[3];    // [640,512]
  const float* Wo = (const float*)d_in[4];    // [1024,640]
  float* out = (float*)d_out;                 // [8,256,64,1024]

  char* ws = (char*)d_ws;
  u16* enc_bf = (u16*)ws;                     // 2,097,152 B
  u16* pred_bf = (u16*)(ws + 2097152);        //   524,288 B
  u16* We_bf = (u16*)(ws + 2621440);          //   655,360 B
  u16* Wp_bf = (u16*)(ws + 3276800);          //   655,360 B
  u16* Wo_bf = (u16*)(ws + 3932160);          // 1,310,720 B -> ends 5,242,880
  float* ep = (float*)(ws + 5242880);         // 5,242,880 B  [2048][640]
  float* pp = (float*)(ws + 10485760);        // 1,310,720 B  [512][640] -> ends 11,796,480
  u16* A_bf = (u16*)(ws + 12582912);          // 167,772,160 B [131072][640] -> ends 180,355,072

  cast5_k<<<2048, 256, 0, stream>>>((const float4*)enc, (const float4*)pred,
                                    (const float4*)We, (const float4*)Wp,
                                    (const float4*)Wo, (ushort4*)ws);

  proj_k<<<dim3(16, 5), 256, 0, stream>>>(enc_bf, We_bf, ep);  // [2048][640]
  proj_k<<<dim3(4, 5), 256, 0, stream>>>(pred_bf, Wp_bf, pp);  // [512][640]

  if (ws_size >= 180355072ull) {
    silu_k<<<2048, 256, 0, stream>>>(ep, pp, A_bf, 10485760);
    gemm256_k<<<2048, 512, 0, stream>>>(A_bf, Wo_bf, out);
  } else {
    joint_k<<<8192, 256, 0, stream>>>(ep, pp, Wo_bf, out);
  }
}

// Round 8
// 348.497 us; speedup vs baseline: 1.0417x; 1.0417x over previous
//
#include <hip/hip_runtime.h>

typedef unsigned short u16;
typedef __attribute__((ext_vector_type(8))) short short8;
typedef __attribute__((ext_vector_type(8))) unsigned short ushort8v;
typedef __attribute__((ext_vector_type(4))) float f32x4;

#define B_ 8
#define T_ 256
#define U_ 64
#define E_ 512
#define J_ 640
#define V_ 1024

__device__ __forceinline__ u16 f2bf(float f) {
  unsigned int u = __float_as_uint(f);
  u += 0x7fffu + ((u >> 16) & 1u);   // round-to-nearest-even
  return (u16)(u >> 16);
}

__device__ __forceinline__ void gload16(const void* g, void* l) {
  __builtin_amdgcn_global_load_lds((const __attribute__((address_space(1))) void*)g,
                                   (__attribute__((address_space(3))) void*)l,
                                   16, 0, 0);
}

// ---------------- fused cast fp32 -> bf16 for all 5 inputs (dsts contiguous in ws) --------
__global__ __launch_bounds__(256) void cast5_k(const float4* __restrict__ s0,
                                               const float4* __restrict__ s1,
                                               const float4* __restrict__ s2,
                                               const float4* __restrict__ s3,
                                               const float4* __restrict__ s4,
                                               ushort4* __restrict__ dst) {
  int i = blockIdx.x * 256 + threadIdx.x;
  const int st = gridDim.x * 256;
  for (; i < 655360; i += st) {
    const float4* s; int off;
    if (i < 262144)      { s = s0; off = 0; }
    else if (i < 327680) { s = s1; off = 262144; }
    else if (i < 409600) { s = s2; off = 327680; }
    else if (i < 491520) { s = s3; off = 409600; }
    else                 { s = s4; off = 491520; }
    float4 v = s[i - off];
    ushort4 o;
    o.x = f2bf(v.x); o.y = f2bf(v.y); o.z = f2bf(v.z); o.w = f2bf(v.w);
    dst[i] = o;
  }
}

// ---------------- projection GEMM (small, latency-tolerant) ----------------
__global__ __launch_bounds__(256) void proj_k(const u16* __restrict__ X,
                                              const u16* __restrict__ W,
                                              float* __restrict__ C) {
  __shared__ __align__(16) u16 As[128 * 32];
  __shared__ __align__(16) u16 Bs[128 * 32];
  const int tid = threadIdx.x;
  const int w = tid >> 6, lane = tid & 63;
  const int wr = w >> 1, wc = w & 1;
  const int m0 = blockIdx.x * 128, n0 = blockIdx.y * 128;
  const int lr = lane & 15, lk = lane >> 4;
  const int r4 = tid >> 2, kq = tid & 3;

  f32x4 acc[4][4] = {};

  for (int ks = 0; ks < E_ / 32; ++ks) {
    const int k0 = ks * 32;
    gload16(X + (size_t)(m0 + r4) * E_ + k0 + kq * 8, (char*)As + w * 1024);
    gload16(X + (size_t)(m0 + 64 + r4) * E_ + k0 + kq * 8, (char*)As + 4096 + w * 1024);
    gload16(W + (size_t)(n0 + r4) * E_ + k0 + kq * 8, (char*)Bs + w * 1024);
    gload16(W + (size_t)(n0 + 64 + r4) * E_ + k0 + kq * 8, (char*)Bs + 4096 + w * 1024);
    __syncthreads();
    short8 a[4], bb[4];
#pragma unroll
    for (int m = 0; m < 4; ++m)
      a[m] = *(const short8*)&As[(wr * 64 + m * 16 + lr) * 32 + lk * 8];
#pragma unroll
    for (int n = 0; n < 4; ++n)
      bb[n] = *(const short8*)&Bs[(wc * 64 + n * 16 + lr) * 32 + lk * 8];
#pragma unroll
    for (int m = 0; m < 4; ++m)
#pragma unroll
      for (int n = 0; n < 4; ++n)
        acc[m][n] = __builtin_amdgcn_mfma_f32_16x16x32_bf16(a[m], bb[n], acc[m][n], 0, 0, 0);
    __syncthreads();
  }

#pragma unroll
  for (int m = 0; m < 4; ++m) {
    const int row = m0 + wr * 64 + m * 16 + lk * 4;
#pragma unroll
    for (int n = 0; n < 4; ++n) {
      const int col = n0 + wc * 64 + n * 16 + lr;
#pragma unroll
      for (int i = 0; i < 4; ++i)
        C[(size_t)(row + i) * J_ + col] = acc[m][n][i];
    }
  }
}

// ---------------- A materializer: A[m][k] = bf16(silu(ep + pp)) ----------------
__global__ __launch_bounds__(256) void silu_k(const float* __restrict__ ep,
                                              const float* __restrict__ pp,
                                              u16* __restrict__ A, int nUnits) {
  int i = blockIdx.x * 256 + threadIdx.x;
  const int st = gridDim.x * 256;
  for (; i < nUnits; i += st) {
    const int m = i / 80;
    const int k0 = (i - m * 80) * 8;
    const int b = m >> 14;
    const int t = (m >> 6) & 255;
    const int uu = m & 63;
    const float* e = ep + (size_t)(b * T_ + t) * J_ + k0;
    const float* p = pp + (size_t)(b * U_ + uu) * J_ + k0;
    union { float4 v[2]; float f[8]; } Ee, Pp;
    Ee.v[0] = *(const float4*)e;      Ee.v[1] = *(const float4*)(e + 4);
    Pp.v[0] = *(const float4*)p;      Pp.v[1] = *(const float4*)(p + 4);
    union { ushort8v v; u16 s[8]; } R;
#pragma unroll
    for (int j = 0; j < 8; ++j) {
      float x = Ee.f[j] + Pp.f[j];
      float s = x * __builtin_amdgcn_rcpf(1.0f + __expf(-x));
      R.s[j] = f2bf(s);
    }
    *(ushort8v*)(A + (size_t)m * J_ + k0) = R.v;
  }
}

// ---------------- main GEMM: 128x128 tile, BK=32, 4 waves, double-buffered ----------------
// TLP-first: 32 KiB LDS + launch_bounds(256,3) -> ~3 independent blocks/CU so one
// block's stage/epilogue stalls overlap another's MFMA (m114 mechanism).
// Counted vmcnt(4): next tile's stage always in flight across barriers.
// Swizzle (0-conflict verified): read chunk lk^((lr>>1)&3); source pre-swizzled.
#define NT 20   // 640/32 K-tiles
__global__ __launch_bounds__(256, 3) void gemm128_k(const u16* __restrict__ A,
                                                    const u16* __restrict__ Bw,
                                                    float* __restrict__ out) {
  __shared__ __align__(16) u16 As[2][128][32];   // 16 KiB
  __shared__ __align__(16) u16 Bs[2][128][32];   // 16 KiB
  const int tid = threadIdx.x;
  const int w = tid >> 6, lane = tid & 63;
  const int wr = w >> 1, wc = w & 1;            // 2x2 waves, wave tile 64x64
  const int lr = lane & 15, lk = lane >> 4;
  const int sx = (lr >> 1) & 3;                 // read-side swizzle term

  // XCD-bijective swizzle: nwg=8192 = 8 XCDs x 1024; 8 N-blocks of an A-panel adjacent
  const int bid = blockIdx.x;
  const int wid = (bid & 7) * 1024 + (bid >> 3);
  const int mb = wid >> 3, nb = wid & 7;
  const size_t m0 = (size_t)mb * 128;
  const int n0 = nb * 128;

  // staging: thread -> (row tid>>2, chunk tid&3); source chunk pre-swizzled
  const int r4 = tid >> 2;
  const int c8s = ((tid & 3) ^ ((tid >> 3) & 3)) * 8;
  const u16* aS = A + (m0 + r4) * J_ + c8s;
  const u16* bS = Bw + (size_t)(n0 + r4) * J_ + c8s;

  f32x4 acc[4][4] = {};

#define STAGE(k0_, bb)                                                        \
  do {                                                                        \
    gload16(aS + (k0_),           (char*)&As[bb][0][0] + tid * 16);           \
    gload16(aS + 64 * J_ + (k0_), (char*)&As[bb][64][0] + tid * 16);          \
    gload16(bS + (k0_),           (char*)&Bs[bb][0][0] + tid * 16);           \
    gload16(bS + 64 * J_ + (k0_), (char*)&Bs[bb][64][0] + tid * 16);          \
  } while (0)

  STAGE(0, 0);
  STAGE(32, 1);

#pragma unroll 1
  for (int t = 0; t < NT; ++t) {
    // stage t complete; stage t+1 (4 loads) stays in flight across the barrier
    if (t < NT - 1) asm volatile("s_waitcnt vmcnt(4)" ::: "memory");
    else            asm volatile("s_waitcnt vmcnt(0)" ::: "memory");
    __builtin_amdgcn_s_barrier();
    __builtin_amdgcn_sched_barrier(0);

    const int bf = t & 1;
    short8 a[4], b[4];
#pragma unroll
    for (int m = 0; m < 4; ++m)
      a[m] = *(const short8*)&As[bf][wr * 64 + m * 16 + lr][(lk ^ sx) * 8];
#pragma unroll
    for (int n = 0; n < 4; ++n)
      b[n] = *(const short8*)&Bs[bf][wc * 64 + n * 16 + lr][(lk ^ sx) * 8];

    __builtin_amdgcn_s_setprio(1);
#pragma unroll
    for (int m = 0; m < 4; ++m)
#pragma unroll
      for (int n = 0; n < 4; ++n)
        acc[m][n] = __builtin_amdgcn_mfma_f32_16x16x32_bf16(a[m], b[n], acc[m][n], 0, 0, 0);
    __builtin_amdgcn_s_setprio(0);

    __builtin_amdgcn_sched_barrier(0);
    __builtin_amdgcn_s_barrier();              // all waves done reading buf[t&1]
    if (t + 2 < NT) STAGE((t + 2) * 32, bf);   // refill the buffer just released
    __builtin_amdgcn_sched_barrier(0);
  }
#undef STAGE

#pragma unroll
  for (int m = 0; m < 4; ++m) {
    const size_t row = m0 + wr * 64 + m * 16 + lk * 4;
#pragma unroll
    for (int n = 0; n < 4; ++n) {
      const int col = n0 + wc * 64 + n * 16 + lr;
#pragma unroll
      for (int i = 0; i < 4; ++i)
        out[(row + i) * V_ + col] = acc[m][n][i];
    }
  }
}

// ---------------- fallback fused kernel (round-1) if ws too small ----------------
__global__ __launch_bounds__(256) void joint_k(const float* __restrict__ ep,
                                               const float* __restrict__ pp,
                                               const u16* __restrict__ Wo,
                                               float* __restrict__ out) {
  __shared__ __align__(16) u16 As[128 * 40];
  __shared__ __align__(16) u16 Bs[128 * 32];
  const int tid = threadIdx.x;
  const int w = tid >> 6, lane = tid & 63;
  const int wr = w >> 1, wc = w & 1;
  const int bid = blockIdx.x;
  const int nb = bid & 7;
  const int mb = bid >> 3;
  const int b = mb >> 7;
  const int t0 = (mb & 127) * 2;
  const int n0 = nb * 128;
  const int lr = lane & 15, lk = lane >> 4;
  const int r = tid >> 1, h = tid & 1;
  const float* eprow = ep + (size_t)((b * T_ + t0 + (r >> 6)) * J_ + h * 16);
  const float* pprow = pp + (size_t)((b * U_ + (r & 63)) * J_ + h * 16);
  u16* awp = &As[r * 40 + h * 16];
  const int r4 = tid >> 2, kq = tid & 3;

  f32x4 acc[4][4] = {};

  for (int ks = 0; ks < J_ / 32; ++ks) {
    const int k0 = ks * 32;
    gload16(Wo + (size_t)(n0 + r4) * J_ + k0 + kq * 8, (char*)Bs + w * 1024);
    gload16(Wo + (size_t)(n0 + 64 + r4) * J_ + k0 + kq * 8, (char*)Bs + 4096 + w * 1024);
    union { float4 v[4]; float f[16]; } Ee, Pp;
#pragma unroll
    for (int j = 0; j < 4; ++j) {
      Ee.v[j] = *(const float4*)(eprow + k0 + j * 4);
      Pp.v[j] = *(const float4*)(pprow + k0 + j * 4);
    }
    union { ushort8v v[2]; u16 s[16]; } R;
#pragma unroll
    for (int j = 0; j < 16; ++j) {
      float x = Ee.f[j] + Pp.f[j];
      float s = x * __builtin_amdgcn_rcpf(1.0f + __expf(-x));
      R.s[j] = f2bf(s);
    }
    *(ushort8v*)awp = R.v[0];
    *(ushort8v*)(awp + 8) = R.v[1];
    __syncthreads();

    short8 a[4], bb[4];
#pragma unroll
    for (int m = 0; m < 4; ++m)
      a[m] = *(const short8*)&As[(wr * 64 + m * 16 + lr) * 40 + lk * 8];
#pragma unroll
    for (int n = 0; n < 4; ++n)
      bb[n] = *(const short8*)&Bs[(wc * 64 + n * 16 + lr) * 32 + lk * 8];
#pragma unroll
    for (int m = 0; m < 4; ++m)
#pragma unroll
      for (int n = 0; n < 4; ++n)
        acc[m][n] = __builtin_amdgcn_mfma_f32_16x16x32_bf16(a[m], bb[n], acc[m][n], 0, 0, 0);
    __syncthreads();
  }

  const size_t mbase = (size_t)mb * 128;
#pragma unroll
  for (int m = 0; m < 4; ++m) {
    const size_t row = mbase + wr * 64 + m * 16 + lk * 4;
#pragma unroll
    for (int n = 0; n < 4; ++n) {
      const int col = n0 + wc * 64 + n * 16 + lr;
#pragma unroll
      for (int i = 0; i < 4; ++i)
        out[(row + i) * V_ + col] = acc[m][n][i];
    }
  }
}

extern "C" void kernel_launch(void* const* d_in, const int* in_sizes, int n_in,
                              void* d_out, int out_size, void* d_ws, size_t ws_size,
                              hipStream_t stream) {
  const float* enc = (const float*)d_in[0];   // [8,256,512]
  const float* pred = (const float*)d_in[1];  // [8,64,512]
  const float* We = (const float*)d_in[2];    // [640,512]
  const float* Wp = (const float*)d_in[3];    // [640,512]
  const float* Wo = (const float*)d_in[4];    // [1024,640]
  float* out = (float*)d_out;                 // [8,256,64,1024]

  char* ws = (char*)d_ws;
  u16* enc_bf = (u16*)ws;                     // 2,097,152 B
  u16* pred_bf = (u16*)(ws + 2097152);        //   524,288 B
  u16* We_bf = (u16*)(ws + 2621440);          //   655,360 B
  u16* Wp_bf = (u16*)(ws + 3276800);          //   655,360 B
  u16* Wo_bf = (u16*)(ws + 3932160);          // 1,310,720 B -> ends 5,242,880
  float* ep = (float*)(ws + 5242880);         // 5,242,880 B  [2048][640]
  float* pp = (float*)(ws + 10485760);        // 1,310,720 B  [512][640] -> ends 11,796,480
  u16* A_bf = (u16*)(ws + 12582912);          // 167,772,160 B [131072][640] -> ends 180,355,072

  cast5_k<<<2048, 256, 0, stream>>>((const float4*)enc, (const float4*)pred,
                                    (const float4*)We, (const float4*)Wp,
                                    (const float4*)Wo, (ushort4*)ws);

  proj_k<<<dim3(16, 5), 256, 0, stream>>>(enc_bf, We_bf, ep);  // [2048][640]
  proj_k<<<dim3(4, 5), 256, 0, stream>>>(pred_bf, Wp_bf, pp);  // [512][640]

  if (ws_size >= 180355072ull) {
    silu_k<<<2048, 256, 0, stream>>>(ep, pp, A_bf, 10485760);
    gemm128_k<<<8192, 256, 0, stream>>>(A_bf, Wo_bf, out);
  } else {
    joint_k<<<8192, 256, 0, stream>>>(ep, pp, Wo_bf, out);
  }
}